// Round 9
// baseline (294.002 us; speedup 1.0000x reference)
//
#include <hip/hip_runtime.h>
#include <hip/hip_bf16.h>

// Problem constants
#define NN 384
#define CUTOFF2 144.0f
#define GAMMA 1.7777778f   // (16/12)^2

// packed B-frag layout per layer (u32 units): [W1b 8192 | We 2048 | W2 8192 | C1 8192]
#define PK_L 26624
#define PK_WE 8192
#define PK_W2 10240
#define PK_C1 18432

#define STG_F32 1152       // per-wave f32 transpose pad

// ws byte offsets
#define O_H    9216        // 384*128 f32
#define O_A    205824      // 384*128 f32
#define O_XA   0
#define O_XB   4608
#define O_HBF0 599040      // 384*128 bf16
#define O_HBF1 697344      // 384*128 bf16 (double buffer)
#define O_MEAN 3076112
#define O_PK   3076160

typedef __bf16 bf16x8 __attribute__((ext_vector_type(8)));
typedef float f32x4 __attribute__((ext_vector_type(4)));

union ER { struct { float dx, dy, dz; unsigned j; } e; uint4 u4; };

__device__ __forceinline__ unsigned short f2bf(float f){
  unsigned u = __float_as_uint(f);
  return (unsigned short)((u + 0x7fffu + ((u >> 16) & 1u)) >> 16);  // RNE
}
__device__ __forceinline__ unsigned pk2(float a, float b){
  return ((unsigned)f2bf(b) << 16) | f2bf(a);
}
__device__ __forceinline__ float silu(float x){ return x / (1.0f + __expf(-x)); }

// ---- scan one row -> LDS edge records {diff,j}; count in pCnt[0]
__device__ __forceinline__ void scan_row1(
    int row, int tid, const float* __restrict__ x, uint4* sEr, int* pCnt){
  if (tid == 0) pCnt[0] = 0;
  __syncthreads();
  {
    float xi0 = x[row*3], xi1 = x[row*3+1], xi2 = x[row*3+2];
    for (int j = tid; j < 384; j += 256) {
      float d0 = xi0-x[j*3], d1 = xi1-x[j*3+1], d2 = xi2-x[j*3+2];
      float dd = d0*d0 + d1*d1 + d2*d2;
      bool msk = ((dd < CUTOFF2) && (j != row)) || (j == row-1) || (j == row+1);
      if (msk) {
        int ss = atomicAdd(pCnt, 1);
        ER er; er.e.dx = d0; er.e.dy = d1; er.e.dz = d2; er.e.j = (unsigned)j;
        sEr[ss] = er.u4;
      }
    }
  }
  __syncthreads();
  {
    int cnt = pCnt[0];
    int p = (32 - (cnt & 31)) & 31;
    if (tid < p) {
      ER er; er.e.dx = 0.f; er.e.dy = 0.f; er.e.dz = 0.f; er.e.j = (unsigned)row;
      sEr[cnt + tid] = er.u4;
    }
  }
  // caller's __syncthreads makes pads visible
}

// ---- C-layout -> A-frag transpose via per-wave f32 LDS pad (wave-private, no fences)
#define TRANSFORM(VA, VB, FA, FB)                                              \
  _Pragma("unroll")                                                            \
  for (int c = 0; c < 4; ++c) {                                                \
    _Pragma("unroll")                                                          \
    for (int tl = 0; tl < 2; ++tl) {                                           \
      int t = 2*c + tl;                                                        \
      _Pragma("unroll")                                                        \
      for (int r = 0; r < 4; ++r) {                                            \
        stg[(quad*4 + r)*36 + tl*16 + col0] = VA[t][r];                        \
        stg[(16 + quad*4 + r)*36 + tl*16 + col0] = VB[t][r];                   \
      }                                                                        \
    }                                                                          \
    float4 lo = *(const float4*)(stg + col0*36 + quad*8);                      \
    float4 hi = *(const float4*)(stg + col0*36 + quad*8 + 4);                  \
    FA[c].u = make_uint4(pk2(lo.x,lo.y), pk2(lo.z,lo.w),                       \
                         pk2(hi.x,hi.y), pk2(hi.z,hi.w));                      \
    float4 lo2 = *(const float4*)(stg + (16 + col0)*36 + quad*8);              \
    float4 hi2 = *(const float4*)(stg + (16 + col0)*36 + quad*8 + 4);          \
    FB[c].u = make_uint4(pk2(lo2.x,lo2.y), pk2(lo2.z,lo2.w),                   \
                         pk2(hi2.x,hi2.y), pk2(hi2.z,hi2.w));                  \
  }

// ---- MFMA edge phase: 1 row, 32-edge units over 4 waves, B-frags from global L2
__device__ __forceinline__ void edge_phase(
    const unsigned short* __restrict__ hbf, const unsigned* __restrict__ pkl,
    float* scratch, const float* pSa, float* pSg, float* pDx,
    int cnt, const uint4* sEr,
    const float* __restrict__ eb2g, const float* __restrict__ cb1g,
    const float* __restrict__ cw2g){
  const int tid = threadIdx.x, q = tid & 63, s = tid >> 6;   // 4 waves
  const int col0 = q & 15, quad = q >> 4;
  float eb2v[8], cb1v[8], cw2v[8];
  #pragma unroll
  for (int t = 0; t < 8; ++t) {
    int c = t*16 + col0;
    eb2v[t] = eb2g[c]; cb1v[t] = cb1g[c]; cw2v[t] = cw2g[c];
  }
  float* stg = scratch + s*STG_F32;
  const f32x4 z4 = {0.f, 0.f, 0.f, 0.f};
  union U8 { uint4 u; bf16x8 v; };

  const int nu = (cnt + 31) >> 5;

  for (int k = s; k < nu; k += 4) {
    int nvalid = cnt - k*32; if (nvalid > 32) nvalid = 32;
    float Aval[8];
    #pragma unroll
    for (int t = 0; t < 8; ++t) Aval[t] = pSa[t*16 + col0];
    ER e0, e1;
    e0.u4 = sEr[k*32 + col0];
    e1.u4 = sEr[k*32 + 16 + col0];
    const int j0 = (int)e0.e.j, j1 = (int)e1.e.j;
    const float d0x = e0.e.dx, d0y = e0.e.dy, d0z = e0.e.dz;
    const float d1x = e1.e.dx, d1y = e1.e.dy, d1z = e1.e.dz;
    const float dd0 = sqrtf(d0x*d0x + d0y*d0y + d0z*d0z);
    const float dd1 = sqrtf(d1x*d1x + d1y*d1y + d1z*d1z);

    U8 ha0[4], ha1[4];
    #pragma unroll
    for (int c = 0; c < 4; ++c) {
      ha0[c].u = *(const uint4*)(hbf + j0*128 + c*32 + quad*8);
      ha1[c].u = *(const uint4*)(hbf + j1*128 + c*32 + quad*8);
    }

    U8 cve0, cve1;
    if (q < 32) {
      #pragma unroll
      for (int tp = 0; tp < 4; ++tp) {
        float k0 = (float)(quad*8 + 2*tp);
        float t00 = dd0 - 0.8f*k0, t01 = dd0 - 0.8f*(k0+1.f);
        float t10 = dd1 - 0.8f*k0, t11 = dd1 - 0.8f*(k0+1.f);
        (&cve0.u.x)[tp] = pk2(__expf(-GAMMA*t00*t00), __expf(-GAMMA*t01*t01));
        (&cve1.u.x)[tp] = pk2(__expf(-GAMMA*t10*t10), __expf(-GAMMA*t11*t11));
      }
    } else { cve0.u = make_uint4(0,0,0,0); cve1.u = make_uint4(0,0,0,0); }

    // GEMM1: m1 = silu(h_j@W1b + e@We + A_i), 32 rows
    f32x4 acc0[8], acc1[8];
    #pragma unroll
    for (int t = 0; t < 8; ++t) { acc0[t] = z4; acc1[t] = z4; }
    #pragma unroll
    for (int t = 0; t < 8; ++t) {
      #pragma unroll
      for (int c = 0; c < 4; ++c) {
        bf16x8 w = *(const bf16x8*)(pkl + ((t*4 + c)*64 + q)*4);
        acc0[t] = __builtin_amdgcn_mfma_f32_16x16x32_bf16(ha0[c].v, w, acc0[t], 0, 0, 0);
        acc1[t] = __builtin_amdgcn_mfma_f32_16x16x32_bf16(ha1[c].v, w, acc1[t], 0, 0, 0);
      }
      bf16x8 we = *(const bf16x8*)(pkl + PK_WE + (t*64 + q)*4);
      acc0[t] = __builtin_amdgcn_mfma_f32_16x16x32_bf16(cve0.v, we, acc0[t], 0, 0, 0);
      acc1[t] = __builtin_amdgcn_mfma_f32_16x16x32_bf16(cve1.v, we, acc1[t], 0, 0, 0);
    }
    #pragma unroll
    for (int t = 0; t < 8; ++t)
      #pragma unroll
      for (int r = 0; r < 4; ++r) {
        acc0[t][r] = silu(acc0[t][r] + Aval[t]);
        acc1[t][r] = silu(acc1[t][r] + Aval[t]);
      }

    U8 a20[4], a21[4];
    TRANSFORM(acc0, acc1, a20, a21);

    // GEMM2: m = silu(m1@eW2 + eb2)
    f32x4 m0[8], m1v[8];
    #pragma unroll
    for (int t = 0; t < 8; ++t) { m0[t] = z4; m1v[t] = z4; }
    #pragma unroll
    for (int t = 0; t < 8; ++t)
      #pragma unroll
      for (int c = 0; c < 4; ++c) {
        bf16x8 w = *(const bf16x8*)(pkl + PK_W2 + ((t*4 + c)*64 + q)*4);
        m0[t] = __builtin_amdgcn_mfma_f32_16x16x32_bf16(a20[c].v, w, m0[t], 0, 0, 0);
        m1v[t] = __builtin_amdgcn_mfma_f32_16x16x32_bf16(a21[c].v, w, m1v[t], 0, 0, 0);
      }
    #pragma unroll
    for (int t = 0; t < 8; ++t) {
      float cs = 0.f;
      #pragma unroll
      for (int r = 0; r < 4; ++r) {
        m0[t][r] = silu(m0[t][r] + eb2v[t]);
        m1v[t][r] = silu(m1v[t][r] + eb2v[t]);
        if (quad*4 + r < nvalid) cs += m0[t][r];
        if (16 + quad*4 + r < nvalid) cs += m1v[t][r];
      }
      cs += __shfl_xor(cs, 16); cs += __shfl_xor(cs, 32);
      if (q < 16) atomicAdd(&pSg[t*16 + q], cs);   // LDS atomic
    }

    U8 a30[4], a31[4];
    TRANSFORM(m0, m1v, a30, a31);

    // GEMM3: c1 = silu(m@cW1 + cb1); w_row = c1 . cW2
    f32x4 c30[8], c31[8];
    #pragma unroll
    for (int t = 0; t < 8; ++t) { c30[t] = z4; c31[t] = z4; }
    #pragma unroll
    for (int t = 0; t < 8; ++t)
      #pragma unroll
      for (int c = 0; c < 4; ++c) {
        bf16x8 w = *(const bf16x8*)(pkl + PK_C1 + ((t*4 + c)*64 + q)*4);
        c30[t] = __builtin_amdgcn_mfma_f32_16x16x32_bf16(a30[c].v, w, c30[t], 0, 0, 0);
        c31[t] = __builtin_amdgcn_mfma_f32_16x16x32_bf16(a31[c].v, w, c31[t], 0, 0, 0);
      }
    float p0[4], p1[4];
    #pragma unroll
    for (int r = 0; r < 4; ++r) {
      float pa = 0.f, pb = 0.f;
      #pragma unroll
      for (int t = 0; t < 8; ++t) {
        pa += silu(c30[t][r] + cb1v[t]) * cw2v[t];
        pb += silu(c31[t][r] + cb1v[t]) * cw2v[t];
      }
      if (quad*4 + r >= nvalid) pa = 0.f;
      if (16 + quad*4 + r >= nvalid) pb = 0.f;
      p0[r] = pa; p1[r] = pb;
    }
    #pragma unroll
    for (int r = 0; r < 4; ++r)
      #pragma unroll
      for (int off = 1; off < 16; off <<= 1) {
        p0[r] += __shfl_xor(p0[r], off);
        p1[r] += __shfl_xor(p1[r], off);
      }
    float dx0 = 0.f, dx1 = 0.f, dx2 = 0.f;
    #pragma unroll
    for (int r = 0; r < 4; ++r) {
      int el = quad*4 + r;
      float s0 = __shfl(d0x, el), s1 = __shfl(d0y, el), s2 = __shfl(d0z, el);
      if (col0 == 0) { dx0 += p0[r]*s0; dx1 += p0[r]*s1; dx2 += p0[r]*s2; }
      float u0 = __shfl(d1x, el), u1 = __shfl(d1y, el), u2 = __shfl(d1z, el);
      if (col0 == 0) { dx0 += p1[r]*u0; dx1 += p1[r]*u1; dx2 += p1[r]*u2; }
    }
    dx0 += __shfl_xor(dx0, 16); dx0 += __shfl_xor(dx0, 32);
    dx1 += __shfl_xor(dx1, 16); dx1 += __shfl_xor(dx1, 32);
    dx2 += __shfl_xor(dx2, 16); dx2 += __shfl_xor(dx2, 32);
    if (q == 0) {
      atomicAdd(&pDx[0], dx0);   // LDS atomic
      atomicAdd(&pDx[1], dx1);
      atomicAdd(&pDx[2], dx2);
    }
  }
}

// ---- node phase (verified R4 math, 1 row / 256 threads)
__device__ __forceinline__ void node_phase(
    const float* __restrict__ nW1l, const float* __restrict__ nb1l,
    const float* __restrict__ nW2l, const float* __restrict__ nb2l,
    const float* __restrict__ eW1n, const float* __restrict__ eb1n,
    unsigned short* __restrict__ hbf_out,
    float* __restrict__ hg, float* __restrict__ Ag,
    float* pSh, float* pSa, const float* pSg,
    float* scratch, int half, int o, int row){
  float* st = scratch; float* part = scratch + 128;

  float aa = 0.f;
  {
    const float* src = half ? pSg : pSh;
    const float* wb  = nW1l + half*128*128;
    float a0=0,a1=0,a2=0,a3=0;
    #pragma unroll 16
    for (int k = 0; k < 128; k += 4) {
      a0 += src[k]   * wb[k*128 + o];
      a1 += src[k+1] * wb[(k+1)*128 + o];
      a2 += src[k+2] * wb[(k+2)*128 + o];
      a3 += src[k+3] * wb[(k+3)*128 + o];
    }
    aa = (a0+a1)+(a2+a3);
    if (half) part[o] = aa;
  }
  __syncthreads();
  if (!half) st[o] = silu(nb1l[o] + aa + part[o]);
  __syncthreads();
  float bb = 0.f;
  {
    int k0 = half*64;
    float b0=0,b1=0,b2=0,b3=0;
    #pragma unroll 16
    for (int k = k0; k < k0+64; k += 4) {
      b0 += st[k]   * nW2l[k*128 + o];
      b1 += st[k+1] * nW2l[(k+1)*128 + o];
      b2 += st[k+2] * nW2l[(k+2)*128 + o];
      b3 += st[k+3] * nW2l[(k+3)*128 + o];
    }
    bb = (b0+b1)+(b2+b3);
    if (half) part[o] = bb;
  }
  __syncthreads();
  if (!half) {
    float hn = pSh[o] + nb2l[o] + bb + part[o];
    pSh[o] = hn;
    hg[row*128 + o] = hn;
    hbf_out[row*128 + o] = f2bf(hn);
  }
  __syncthreads();
  float cc = 0.f;
  {
    int k0 = half*64;
    float c0=0,c1=0,c2=0,c3=0;
    #pragma unroll 16
    for (int k = k0; k < k0+64; k += 4) {
      c0 += pSh[k]   * eW1n[k*128 + o];
      c1 += pSh[k+1] * eW1n[(k+1)*128 + o];
      c2 += pSh[k+2] * eW1n[(k+2)*128 + o];
      c3 += pSh[k+3] * eW1n[(k+3)*128 + o];
    }
    cc = (c0+c1)+(c2+c3);
    if (half) part[o] = cc;
  }
  __syncthreads();
  if (!half) Ag[row*128 + o] = eb1n[o] + cc + part[o];
}

// ---- K1: pack + mean + proj + A0 (verified R8 body; block b computes rows {b, b+256})
__global__ __launch_bounds__(512) void k_init(
    const float* __restrict__ eW1, const float* __restrict__ eW2,
    const float* __restrict__ cW1, unsigned* __restrict__ pk,
    const float* __restrict__ anchor, const float* __restrict__ z,
    const float* __restrict__ pW, const float* __restrict__ pbias,
    const float* __restrict__ eb1, float* __restrict__ h,
    unsigned short* __restrict__ hbf, float* __restrict__ A,
    float* __restrict__ meanw){
  __shared__ float sb2[2*768];
  __shared__ float ssum[3];
  const int b = blockIdx.x, tid = threadIdx.x;
  const int rowsel = tid >> 8, half = (tid >> 7) & 1, o = tid & 127;
  // weight pack (256*512 = 131072 slots cover 3*PK_L = 79872)
  {
    int t = b*512 + tid;
    if (t < 3*PK_L) {
      int layer = t / PK_L, r = t % PK_L;
      const float* src; int fr; int isWe = 0;
      if (r < PK_WE)        { fr = r;          src = eW1 + (layer*272 + 128)*128; }
      else if (r < PK_W2)   { fr = r - PK_WE;  src = eW1 + (layer*272 + 256)*128; isWe = 1; }
      else if (r < PK_C1)   { fr = r - PK_W2;  src = eW2 + layer*128*128; }
      else                  { fr = r - PK_C1;  src = cW1 + layer*128*128; }
      int tp = fr & 3, ll = (fr >> 2) & 63, nc = fr >> 8;
      int n, k;
      if (!isWe) { n = nc >> 2; int c = nc & 3; k = c*32 + ((ll>>4)<<3) + 2*tp; }
      else       { n = nc;                      k = ((ll>>4)<<3) + 2*tp; }
      int nn2 = n*16 + (ll & 15);
      float w0, w1;
      if (isWe) { w0 = (k < 16)   ? src[k*128+nn2]     : 0.f;
                  w1 = (k+1 < 16) ? src[(k+1)*128+nn2] : 0.f; }
      else      { w0 = src[k*128+nn2]; w1 = src[(k+1)*128+nn2]; }
      pk[t] = ((unsigned)f2bf(w1) << 16) | f2bf(w0);
    }
  }
  if (b == 0) {                          // anchor mean
    if (tid < 3) ssum[tid] = 0.f;
    __syncthreads();
    if (tid < 384) {
      atomicAdd(&ssum[0], anchor[tid*3]);
      atomicAdd(&ssum[1], anchor[tid*3+1]);
      atomicAdd(&ssum[2], anchor[tid*3+2]);
    }
    __syncthreads();
    if (tid < 3) meanw[tid] = ssum[tid]*(1.f/384.f);
  }
  // proj + A-precompute for own rows
  const int row = b + 256*rowsel;
  const bool v = row < NN;
  float* sb = sb2 + rowsel*768;
  float* sh = sb; float* part = sb + 512; float* sz = sb + 640;
  if (v && half == 0 && o < 64) sz[o] = z[row*64 + o];
  __syncthreads();
  float pp = 0.f;
  if (v) {
    int k0 = half*32;
    float p0=0,p1=0,p2=0,p3=0;
    #pragma unroll 8
    for (int k = k0; k < k0+32; k += 4) {
      p0 += sz[k]   * pW[k*128 + o];
      p1 += sz[k+1] * pW[(k+1)*128 + o];
      p2 += sz[k+2] * pW[(k+2)*128 + o];
      p3 += sz[k+3] * pW[(k+3)*128 + o];
    }
    pp = (p0+p1)+(p2+p3);
    if (half) part[o] = pp;
  }
  __syncthreads();
  if (v && !half) {
    float hh = pbias[o] + pp + part[o];
    h[row*128 + o] = hh; sh[o] = hh;
    hbf[row*128 + o] = f2bf(hh);
  }
  __syncthreads();
  float cc = 0.f;
  if (v) {
    int k0 = half*64;
    float c0=0,c1=0,c2=0,c3=0;
    #pragma unroll 16
    for (int k = k0; k < k0+64; k += 4) {
      c0 += sh[k]   * eW1[k*128 + o];
      c1 += sh[k+1] * eW1[(k+1)*128 + o];
      c2 += sh[k+2] * eW1[(k+2)*128 + o];
      c3 += sh[k+3] * eW1[(k+3)*128 + o];
    }
    cc = (c0+c1)+(c2+c3);
    if (half) part[o] = cc;
  }
  __syncthreads();
  if (v && !half) A[row*128 + o] = eb1[o] + cc + part[o];
}

// ---- K2: one layer, one row per block (384 blocks x 256 thr), weights from L2
__global__ __launch_bounds__(256, 2) void k_layer(
    const unsigned* __restrict__ pkl,
    const float* __restrict__ x_src, float* __restrict__ x_dst,
    const unsigned short* __restrict__ hbf_in, unsigned short* __restrict__ hbf_out,
    float* __restrict__ h, float* __restrict__ A,
    const float* __restrict__ eb2l, const float* __restrict__ cb1l,
    const float* __restrict__ cw2l,
    const float* __restrict__ nW1l, const float* __restrict__ nb1l,
    const float* __restrict__ nW2l, const float* __restrict__ nb2l,
    const float* __restrict__ eW1n, const float* __restrict__ eb1n,
    const float* __restrict__ meanp, int do_node){
  __shared__ float scratch[4*STG_F32];   // 18432 B: transpose pads + node temp
  __shared__ float pSh[128], pSa[128], pSg[128], pDx[4];
  __shared__ int pCnt[4];
  __shared__ uint4 sEr[384];             // 6144 B edge records
  const int row = blockIdx.x, tid = threadIdx.x;
  const int half = tid >> 7, o = tid & 127;

  // load own-row h/A, zero agg/dx
  if (tid < 128) { pSh[tid] = h[row*128 + tid]; pSg[tid] = 0.f; }
  else           { pSa[o] = A[row*128 + o]; if (o < 4) pDx[o] = 0.f; }
  // build radius graph for own row into LDS (internal syncthreads)
  scan_row1(row, tid, x_src, sEr, pCnt);
  __syncthreads();
  edge_phase(hbf_in, pkl, scratch, pSa, pSg, pDx, pCnt[0], sEr,
             eb2l, cb1l, cw2l);
  __syncthreads();
  if (tid < 3) {
    float xn = x_src[row*3 + tid] + pDx[tid];
    x_dst[row*3 + tid] = meanp ? (xn - meanp[tid]) : xn;
  }
  if (do_node)
    node_phase(nW1l, nb1l, nW2l, nb2l, eW1n, eb1n, hbf_out, h, A,
               pSh, pSa, pSg, scratch, half, o, row);
}

extern "C" void kernel_launch(void* const* d_in, const int* in_sizes, int n_in,
                              void* d_out, int out_size, void* d_ws, size_t ws_size,
                              hipStream_t stream){
  const float* z      = (const float*)d_in[0];
  const float* anchor = (const float*)d_in[1];
  const float* projW  = (const float*)d_in[2];
  const float* projb  = (const float*)d_in[3];
  const float* eW1    = (const float*)d_in[4];
  const float* eb1    = (const float*)d_in[5];
  const float* eW2    = (const float*)d_in[6];
  const float* eb2    = (const float*)d_in[7];
  const float* nW1    = (const float*)d_in[8];
  const float* nb1    = (const float*)d_in[9];
  const float* nW2    = (const float*)d_in[10];
  const float* nb2    = (const float*)d_in[11];
  const float* cW1    = (const float*)d_in[12];
  const float* cb1    = (const float*)d_in[13];
  const float* cW2    = (const float*)d_in[14];
  float* out = (float*)d_out;

  char* w = (char*)d_ws;
  float* xA  = (float*)(w + O_XA);
  float* xB  = (float*)(w + O_XB);
  float* h   = (float*)(w + O_H);
  float* A   = (float*)(w + O_A);
  unsigned short* hbf0 = (unsigned short*)(w + O_HBF0);
  unsigned short* hbf1 = (unsigned short*)(w + O_HBF1);
  float* meanw = (float*)(w + O_MEAN);
  unsigned* pk = (unsigned*)(w + O_PK);

  k_init<<<256, 512, 0, stream>>>(eW1, eW2, cW1, pk, anchor, z, projW, projb,
                                  eb1, h, hbf0, A, meanw);
  // layer 0: anchor -> xB; reads hbf0, node -> hbf1, A(l1)
  k_layer<<<384, 256, 0, stream>>>(pk, anchor, xB, hbf0, hbf1, h, A,
      eb2, cb1, cW2,
      nW1, nb1, nW2, nb2, eW1 + 272*128, eb1 + 128,
      (const float*)nullptr, 1);
  // layer 1: xB -> xA; reads hbf1, node -> hbf0, A(l2)
  k_layer<<<384, 256, 0, stream>>>(pk + PK_L, xB, xA, hbf1, hbf0, h, A,
      eb2 + 128, cb1 + 128, cW2 + 128,
      nW1 + 256*128, nb1 + 128, nW2 + 128*128, nb2 + 128,
      eW1 + 2*272*128, eb1 + 256,
      (const float*)nullptr, 1);
  // layer 2: xA -> out (centered); reads hbf0 (layer-1 node output); no node
  k_layer<<<384, 256, 0, stream>>>(pk + 2*PK_L, xA, out, hbf0, hbf1, h, A,
      eb2 + 256, cb1 + 256, cW2 + 256,
      nW1, nb1, nW2, nb2, eW1, eb1,
      meanw, 0);
}

// Round 10
// 210.107 us; speedup vs baseline: 1.3993x; 1.3993x over previous
//
#include <hip/hip_runtime.h>
#include <hip/hip_bf16.h>

// Problem constants
#define NN 384
#define CUTOFF2 144.0f
#define GAMMA 1.7777778f   // (16/12)^2

// packed B-frag layout per layer (u32 units): [W1b 8192 | We 2048 | W2 8192 | C1 8192]
#define PK_L 26624
#define PK_WE 8192
#define PK_W2 10240
#define PK_C1 18432

#define STG_F32 576                        // per-wave 16x36 f32 transpose pad (2-pass)
#define SCRATCH_B (16*STG_F32*4)           // 36864 B (16 waves)
#define PERSIST_OFF (PK_L*4 + SCRATCH_B)   // 143360 B
// persist: pSh 1024 | pSa 1024 | pSg 1024 | pDx 32 | pCnt 16 | pad | sErec 12288 @3120
#define K_SMEM (PERSIST_OFF + 15408)       // 158768 B <= 160 KiB -> 1 block/CU

// ws byte offsets
#define O_H    9216        // 384*128 f32
#define O_A    205824      // 384*128 f32
#define O_XA   0
#define O_XB   4608
#define O_HBF0 599040      // 384*128 bf16
#define O_HBF1 697344      // 384*128 bf16 (double buffer)
#define O_MEAN 3076112
#define O_PK   3076160

typedef __bf16 bf16x8 __attribute__((ext_vector_type(8)));
typedef float f32x4 __attribute__((ext_vector_type(4)));

union ER { struct { float dx, dy, dz; unsigned j; } e; uint4 u4; };

__device__ __forceinline__ unsigned short f2bf(float f){
  unsigned u = __float_as_uint(f);
  return (unsigned short)((u + 0x7fffu + ((u >> 16) & 1u)) >> 16);  // RNE
}
__device__ __forceinline__ unsigned pk2(float a, float b){
  return ((unsigned)f2bf(b) << 16) | f2bf(a);
}
__device__ __forceinline__ float silu(float x){ return x / (1.0f + __expf(-x)); }

// ---- scan own rows (2 rows x 512 thr) -> LDS edge records; count in pCnt[rsel]
__device__ __forceinline__ void scan_rows2(
    int row, int rsel, int t512, bool v, const float* __restrict__ x,
    uint4* sEr, int* pCnt){
  if (t512 == 0) pCnt[rsel] = 0;
  __syncthreads();
  if (v && t512 < 384) {
    int j = t512;
    float xi0 = x[row*3], xi1 = x[row*3+1], xi2 = x[row*3+2];
    float d0 = xi0-x[j*3], d1 = xi1-x[j*3+1], d2 = xi2-x[j*3+2];
    float dd = d0*d0 + d1*d1 + d2*d2;
    bool msk = ((dd < CUTOFF2) && (j != row)) || (j == row-1) || (j == row+1);
    if (msk) {
      int ss = atomicAdd(&pCnt[rsel], 1);
      ER er; er.e.dx = d0; er.e.dy = d1; er.e.dz = d2; er.e.j = (unsigned)j;
      sEr[rsel*384 + ss] = er.u4;
    }
  }
  __syncthreads();
  if (v) {
    int cnt = pCnt[rsel];
    int p = (32 - (cnt & 31)) & 31;
    if (t512 < p) {
      ER er; er.e.dx = 0.f; er.e.dy = 0.f; er.e.dz = 0.f; er.e.j = (unsigned)row;
      sEr[rsel*384 + cnt + t512] = er.u4;
    }
  }
  // caller's __syncthreads (pre-edge) makes pads visible
}

// ---- C-layout -> A-frag transpose via per-wave 16x36 f32 pad, two passes per c
// (wave-private; same-wave LDS ops are in-order so VB overwrite follows FA read)
#define TRANSFORM2(VA, VB, FA, FB)                                             \
  _Pragma("unroll")                                                            \
  for (int c = 0; c < 4; ++c) {                                                \
    _Pragma("unroll")                                                          \
    for (int tl = 0; tl < 2; ++tl) {                                           \
      int t = 2*c + tl;                                                        \
      _Pragma("unroll")                                                        \
      for (int r = 0; r < 4; ++r)                                              \
        stg[(quad*4 + r)*36 + tl*16 + col0] = VA[t][r];                        \
    }                                                                          \
    { float4 lo = *(const float4*)(stg + col0*36 + quad*8);                    \
      float4 hi = *(const float4*)(stg + col0*36 + quad*8 + 4);                \
      FA[c].u = make_uint4(pk2(lo.x,lo.y), pk2(lo.z,lo.w),                     \
                           pk2(hi.x,hi.y), pk2(hi.z,hi.w)); }                  \
    _Pragma("unroll")                                                          \
    for (int tl = 0; tl < 2; ++tl) {                                           \
      int t = 2*c + tl;                                                        \
      _Pragma("unroll")                                                        \
      for (int r = 0; r < 4; ++r)                                              \
        stg[(quad*4 + r)*36 + tl*16 + col0] = VB[t][r];                        \
    }                                                                          \
    { float4 lo2 = *(const float4*)(stg + col0*36 + quad*8);                   \
      float4 hi2 = *(const float4*)(stg + col0*36 + quad*8 + 4);               \
      FB[c].u = make_uint4(pk2(lo2.x,lo2.y), pk2(lo2.z,lo2.w),                 \
                           pk2(hi2.x,hi2.y), pk2(hi2.z,hi2.w)); }              \
  }

// ---- MFMA edge phase: 32-edge units over 16 waves, LDS weights (R8 math)
__device__ __forceinline__ void edge_phase(
    const unsigned short* __restrict__ hbf,
    const unsigned* smem, float* scratch,
    const float* pSa, float* pSg, float* pDx, const int* pCnt, const uint4* sEr,
    const float* __restrict__ eb2g, const float* __restrict__ cb1g,
    const float* __restrict__ cw2g, int valid1){
  const int tid = threadIdx.x, q = tid & 63, s = tid >> 6;   // 16 waves
  const int col0 = q & 15, quad = q >> 4;
  float eb2v[8], cb1v[8], cw2v[8];
  #pragma unroll
  for (int t = 0; t < 8; ++t) {
    int c = t*16 + col0;
    eb2v[t] = eb2g[c]; cb1v[t] = cb1g[c]; cw2v[t] = cw2g[c];
  }
  float* stg = scratch + s*STG_F32;
  const f32x4 z4 = {0.f, 0.f, 0.f, 0.f};
  union U8 { uint4 u; bf16x8 v; };

  const int nu0 = (pCnt[0] + 31) >> 5;
  const int nu1 = valid1 ? ((pCnt[1] + 31) >> 5) : 0;
  const int nu = nu0 + nu1;

  for (int k = s; k < nu; k += 16) {
    const int rs = (k < nu0) ? 0 : 1;
    const int ub = (k < nu0) ? k : k - nu0;
    int nvalid = pCnt[rs] - ub*32; if (nvalid > 32) nvalid = 32;
    float Aval[8];
    #pragma unroll
    for (int t = 0; t < 8; ++t) Aval[t] = pSa[rs*128 + t*16 + col0];
    ER e0, e1;
    e0.u4 = sEr[rs*384 + ub*32 + col0];
    e1.u4 = sEr[rs*384 + ub*32 + 16 + col0];
    const int j0 = (int)e0.e.j, j1 = (int)e1.e.j;
    const float d0x = e0.e.dx, d0y = e0.e.dy, d0z = e0.e.dz;
    const float d1x = e1.e.dx, d1y = e1.e.dy, d1z = e1.e.dz;
    const float dd0 = sqrtf(d0x*d0x + d0y*d0y + d0z*d0z);
    const float dd1 = sqrtf(d1x*d1x + d1y*d1y + d1z*d1z);

    U8 ha0[4], ha1[4];
    #pragma unroll
    for (int c = 0; c < 4; ++c) {
      ha0[c].u = *(const uint4*)(hbf + j0*128 + c*32 + quad*8);
      ha1[c].u = *(const uint4*)(hbf + j1*128 + c*32 + quad*8);
    }

    U8 cve0, cve1;
    if (q < 32) {
      #pragma unroll
      for (int tp = 0; tp < 4; ++tp) {
        float k0 = (float)(quad*8 + 2*tp);
        float t00 = dd0 - 0.8f*k0, t01 = dd0 - 0.8f*(k0+1.f);
        float t10 = dd1 - 0.8f*k0, t11 = dd1 - 0.8f*(k0+1.f);
        (&cve0.u.x)[tp] = pk2(__expf(-GAMMA*t00*t00), __expf(-GAMMA*t01*t01));
        (&cve1.u.x)[tp] = pk2(__expf(-GAMMA*t10*t10), __expf(-GAMMA*t11*t11));
      }
    } else { cve0.u = make_uint4(0,0,0,0); cve1.u = make_uint4(0,0,0,0); }

    // GEMM1: m1 = silu(h_j@W1b + e@We + A_i), 32 rows
    f32x4 acc0[8], acc1[8];
    #pragma unroll
    for (int t = 0; t < 8; ++t) { acc0[t] = z4; acc1[t] = z4; }
    #pragma unroll
    for (int t = 0; t < 8; ++t) {
      #pragma unroll
      for (int c = 0; c < 4; ++c) {
        bf16x8 w = *(const bf16x8*)(smem + ((t*4 + c)*64 + q)*4);
        acc0[t] = __builtin_amdgcn_mfma_f32_16x16x32_bf16(ha0[c].v, w, acc0[t], 0, 0, 0);
        acc1[t] = __builtin_amdgcn_mfma_f32_16x16x32_bf16(ha1[c].v, w, acc1[t], 0, 0, 0);
      }
      bf16x8 we = *(const bf16x8*)(smem + PK_WE + (t*64 + q)*4);
      acc0[t] = __builtin_amdgcn_mfma_f32_16x16x32_bf16(cve0.v, we, acc0[t], 0, 0, 0);
      acc1[t] = __builtin_amdgcn_mfma_f32_16x16x32_bf16(cve1.v, we, acc1[t], 0, 0, 0);
    }
    #pragma unroll
    for (int t = 0; t < 8; ++t)
      #pragma unroll
      for (int r = 0; r < 4; ++r) {
        acc0[t][r] = silu(acc0[t][r] + Aval[t]);
        acc1[t][r] = silu(acc1[t][r] + Aval[t]);
      }

    U8 a20[4], a21[4];
    TRANSFORM2(acc0, acc1, a20, a21);

    // GEMM2: m = silu(m1@eW2 + eb2)
    f32x4 m0[8], m1v[8];
    #pragma unroll
    for (int t = 0; t < 8; ++t) { m0[t] = z4; m1v[t] = z4; }
    #pragma unroll
    for (int t = 0; t < 8; ++t)
      #pragma unroll
      for (int c = 0; c < 4; ++c) {
        bf16x8 w = *(const bf16x8*)(smem + PK_W2 + ((t*4 + c)*64 + q)*4);
        m0[t] = __builtin_amdgcn_mfma_f32_16x16x32_bf16(a20[c].v, w, m0[t], 0, 0, 0);
        m1v[t] = __builtin_amdgcn_mfma_f32_16x16x32_bf16(a21[c].v, w, m1v[t], 0, 0, 0);
      }
    #pragma unroll
    for (int t = 0; t < 8; ++t) {
      float cs = 0.f;
      #pragma unroll
      for (int r = 0; r < 4; ++r) {
        m0[t][r] = silu(m0[t][r] + eb2v[t]);
        m1v[t][r] = silu(m1v[t][r] + eb2v[t]);
        if (quad*4 + r < nvalid) cs += m0[t][r];
        if (16 + quad*4 + r < nvalid) cs += m1v[t][r];
      }
      cs += __shfl_xor(cs, 16); cs += __shfl_xor(cs, 32);
      if (q < 16) atomicAdd(&pSg[rs*128 + t*16 + q], cs);   // LDS atomic
    }

    U8 a30[4], a31[4];
    TRANSFORM2(m0, m1v, a30, a31);

    // GEMM3: c1 = silu(m@cW1 + cb1); w_row = c1 . cW2
    f32x4 c30[8], c31[8];
    #pragma unroll
    for (int t = 0; t < 8; ++t) { c30[t] = z4; c31[t] = z4; }
    #pragma unroll
    for (int t = 0; t < 8; ++t)
      #pragma unroll
      for (int c = 0; c < 4; ++c) {
        bf16x8 w = *(const bf16x8*)(smem + PK_C1 + ((t*4 + c)*64 + q)*4);
        c30[t] = __builtin_amdgcn_mfma_f32_16x16x32_bf16(a30[c].v, w, c30[t], 0, 0, 0);
        c31[t] = __builtin_amdgcn_mfma_f32_16x16x32_bf16(a31[c].v, w, c31[t], 0, 0, 0);
      }
    float p0[4], p1[4];
    #pragma unroll
    for (int r = 0; r < 4; ++r) {
      float pa = 0.f, pb = 0.f;
      #pragma unroll
      for (int t = 0; t < 8; ++t) {
        pa += silu(c30[t][r] + cb1v[t]) * cw2v[t];
        pb += silu(c31[t][r] + cb1v[t]) * cw2v[t];
      }
      if (quad*4 + r >= nvalid) pa = 0.f;
      if (16 + quad*4 + r >= nvalid) pb = 0.f;
      p0[r] = pa; p1[r] = pb;
    }
    #pragma unroll
    for (int r = 0; r < 4; ++r)
      #pragma unroll
      for (int off = 1; off < 16; off <<= 1) {
        p0[r] += __shfl_xor(p0[r], off);
        p1[r] += __shfl_xor(p1[r], off);
      }
    float dx0 = 0.f, dx1 = 0.f, dx2 = 0.f;
    #pragma unroll
    for (int r = 0; r < 4; ++r) {
      int el = quad*4 + r;
      float s0 = __shfl(d0x, el), s1 = __shfl(d0y, el), s2 = __shfl(d0z, el);
      if (col0 == 0) { dx0 += p0[r]*s0; dx1 += p0[r]*s1; dx2 += p0[r]*s2; }
      float u0 = __shfl(d1x, el), u1 = __shfl(d1y, el), u2 = __shfl(d1z, el);
      if (col0 == 0) { dx0 += p1[r]*u0; dx1 += p1[r]*u1; dx2 += p1[r]*u2; }
    }
    dx0 += __shfl_xor(dx0, 16); dx0 += __shfl_xor(dx0, 32);
    dx1 += __shfl_xor(dx1, 16); dx1 += __shfl_xor(dx1, 32);
    dx2 += __shfl_xor(dx2, 16); dx2 += __shfl_xor(dx2, 32);
    if (q == 0) {
      atomicAdd(&pDx[rs*4 + 0], dx0);   // LDS atomic
      atomicAdd(&pDx[rs*4 + 1], dx1);
      atomicAdd(&pDx[rs*4 + 2], dx2);
    }
  }
}

// ---- node phase: 2 rows x 128 outputs x split-K-4 (1024 threads)
__device__ __forceinline__ void node_phase4(
    const float* __restrict__ nW1l, const float* __restrict__ nb1l,
    const float* __restrict__ nW2l, const float* __restrict__ nb2l,
    const float* __restrict__ eW1n, const float* __restrict__ eb1n,
    unsigned short* __restrict__ hbf_out,
    float* __restrict__ hg, float* __restrict__ Ag,
    float* pSh, float* pSa, const float* pSg,
    float* nodeScr, int rsel, int q4, int o, int row, bool v){
  float* st   = nodeScr + rsel*512;
  float* part = st + 128;              // 3 x 128 partials

  // matvec1: aa over nW1[256][128]; rows 0-127 x h, 128-255 x agg; q4 owns 64 rows
  float aa = 0.f;
  if (v) {
    int kb = q4*64;
    const float* srcv = (q4 < 2) ? (pSh + rsel*128) : (pSg + rsel*128);
    int off = (q4 < 2) ? kb : kb - 128;
    float a0=0,a1=0,a2=0,a3=0;
    #pragma unroll 8
    for (int i = 0; i < 64; i += 4) {
      a0 += srcv[off+i]   * nW1l[(kb+i)*128 + o];
      a1 += srcv[off+i+1] * nW1l[(kb+i+1)*128 + o];
      a2 += srcv[off+i+2] * nW1l[(kb+i+2)*128 + o];
      a3 += srcv[off+i+3] * nW1l[(kb+i+3)*128 + o];
    }
    aa = (a0+a1)+(a2+a3);
    if (q4) part[(q4-1)*128 + o] = aa;
  }
  __syncthreads();
  if (v && q4 == 0)
    st[o] = silu(nb1l[o] + aa + part[o] + part[128+o] + part[256+o]);
  __syncthreads();
  // matvec2: bb = st@nW2, q4 owns 32 rows
  float bb = 0.f;
  if (v) {
    int kb = q4*32;
    float b0=0,b1=0,b2=0,b3=0;
    #pragma unroll 8
    for (int i = 0; i < 32; i += 4) {
      b0 += st[kb+i]   * nW2l[(kb+i)*128 + o];
      b1 += st[kb+i+1] * nW2l[(kb+i+1)*128 + o];
      b2 += st[kb+i+2] * nW2l[(kb+i+2)*128 + o];
      b3 += st[kb+i+3] * nW2l[(kb+i+3)*128 + o];
    }
    bb = (b0+b1)+(b2+b3);
    if (q4) part[(q4-1)*128 + o] = bb;
  }
  __syncthreads();
  if (v && q4 == 0) {
    float hn = pSh[rsel*128 + o] + nb2l[o] + bb + part[o] + part[128+o] + part[256+o];
    pSh[rsel*128 + o] = hn;
    hg[row*128 + o] = hn;
    hbf_out[row*128 + o] = f2bf(hn);
  }
  __syncthreads();
  // matvec3: cc = h_new@eW1n, q4 owns 32 rows
  float cc = 0.f;
  if (v) {
    const float* shn = pSh + rsel*128;
    int kb = q4*32;
    float c0=0,c1=0,c2=0,c3=0;
    #pragma unroll 8
    for (int i = 0; i < 32; i += 4) {
      c0 += shn[kb+i]   * eW1n[(kb+i)*128 + o];
      c1 += shn[kb+i+1] * eW1n[(kb+i+1)*128 + o];
      c2 += shn[kb+i+2] * eW1n[(kb+i+2)*128 + o];
      c3 += shn[kb+i+3] * eW1n[(kb+i+3)*128 + o];
    }
    cc = (c0+c1)+(c2+c3);
    if (q4) part[(q4-1)*128 + o] = cc;
  }
  __syncthreads();
  if (v && q4 == 0)
    Ag[row*128 + o] = eb1n[o] + cc + part[o] + part[128+o] + part[256+o];
}

// ---- K1: pack + mean + proj + A0 (verified R8 body)
__global__ __launch_bounds__(512) void k_init(
    const float* __restrict__ eW1, const float* __restrict__ eW2,
    const float* __restrict__ cW1, unsigned* __restrict__ pk,
    const float* __restrict__ anchor, const float* __restrict__ z,
    const float* __restrict__ pW, const float* __restrict__ pbias,
    const float* __restrict__ eb1, float* __restrict__ h,
    unsigned short* __restrict__ hbf, float* __restrict__ A,
    float* __restrict__ meanw){
  __shared__ float sb2[2*768];
  __shared__ float ssum[3];
  const int b = blockIdx.x, tid = threadIdx.x;
  const int rowsel = tid >> 8, half = (tid >> 7) & 1, o = tid & 127;
  {
    int t = b*512 + tid;
    if (t < 3*PK_L) {
      int layer = t / PK_L, r = t % PK_L;
      const float* src; int fr; int isWe = 0;
      if (r < PK_WE)        { fr = r;          src = eW1 + (layer*272 + 128)*128; }
      else if (r < PK_W2)   { fr = r - PK_WE;  src = eW1 + (layer*272 + 256)*128; isWe = 1; }
      else if (r < PK_C1)   { fr = r - PK_W2;  src = eW2 + layer*128*128; }
      else                  { fr = r - PK_C1;  src = cW1 + layer*128*128; }
      int tp = fr & 3, ll = (fr >> 2) & 63, nc = fr >> 8;
      int n, k;
      if (!isWe) { n = nc >> 2; int c = nc & 3; k = c*32 + ((ll>>4)<<3) + 2*tp; }
      else       { n = nc;                      k = ((ll>>4)<<3) + 2*tp; }
      int nn2 = n*16 + (ll & 15);
      float w0, w1;
      if (isWe) { w0 = (k < 16)   ? src[k*128+nn2]     : 0.f;
                  w1 = (k+1 < 16) ? src[(k+1)*128+nn2] : 0.f; }
      else      { w0 = src[k*128+nn2]; w1 = src[(k+1)*128+nn2]; }
      pk[t] = ((unsigned)f2bf(w1) << 16) | f2bf(w0);
    }
  }
  if (b == 0) {
    if (tid < 3) ssum[tid] = 0.f;
    __syncthreads();
    if (tid < 384) {
      atomicAdd(&ssum[0], anchor[tid*3]);
      atomicAdd(&ssum[1], anchor[tid*3+1]);
      atomicAdd(&ssum[2], anchor[tid*3+2]);
    }
    __syncthreads();
    if (tid < 3) meanw[tid] = ssum[tid]*(1.f/384.f);
  }
  const int row = b + 256*rowsel;
  const bool v = row < NN;
  float* sb = sb2 + rowsel*768;
  float* sh = sb; float* part = sb + 512; float* sz = sb + 640;
  if (v && half == 0 && o < 64) sz[o] = z[row*64 + o];
  __syncthreads();
  float pp = 0.f;
  if (v) {
    int k0 = half*32;
    float p0=0,p1=0,p2=0,p3=0;
    #pragma unroll 8
    for (int k = k0; k < k0+32; k += 4) {
      p0 += sz[k]   * pW[k*128 + o];
      p1 += sz[k+1] * pW[(k+1)*128 + o];
      p2 += sz[k+2] * pW[(k+2)*128 + o];
      p3 += sz[k+3] * pW[(k+3)*128 + o];
    }
    pp = (p0+p1)+(p2+p3);
    if (half) part[o] = pp;
  }
  __syncthreads();
  if (v && !half) {
    float hh = pbias[o] + pp + part[o];
    h[row*128 + o] = hh; sh[o] = hh;
    hbf[row*128 + o] = f2bf(hh);
  }
  __syncthreads();
  float cc = 0.f;
  if (v) {
    int k0 = half*64;
    float c0=0,c1=0,c2=0,c3=0;
    #pragma unroll 16
    for (int k = k0; k < k0+64; k += 4) {
      c0 += sh[k]   * eW1[k*128 + o];
      c1 += sh[k+1] * eW1[(k+1)*128 + o];
      c2 += sh[k+2] * eW1[(k+2)*128 + o];
      c3 += sh[k+3] * eW1[(k+3)*128 + o];
    }
    cc = (c0+c1)+(c2+c3);
    if (half) part[o] = cc;
  }
  __syncthreads();
  if (v && !half) A[row*128 + o] = eb1[o] + cc + part[o];
}

// ---- K2: one layer, 2 rows/block, 1024 threads (16 waves = 4/SIMD)
__global__ __launch_bounds__(1024) void k_layer(
    const unsigned* __restrict__ pkl,
    const float* __restrict__ x_src, float* __restrict__ x_dst,
    const unsigned short* __restrict__ hbf_in, unsigned short* __restrict__ hbf_out,
    float* __restrict__ h, float* __restrict__ A,
    const float* __restrict__ eb2l, const float* __restrict__ cb1l,
    const float* __restrict__ cw2l,
    const float* __restrict__ nW1l, const float* __restrict__ nb1l,
    const float* __restrict__ nW2l, const float* __restrict__ nb2l,
    const float* __restrict__ eW1n, const float* __restrict__ eb1n,
    const float* __restrict__ meanp, int do_node){
  extern __shared__ unsigned smem[];
  const int b = blockIdx.x, tid = threadIdx.x;
  const int rsel = tid >> 9, t512 = tid & 511;
  const int q4 = (tid >> 7) & 3, o = tid & 127;
  const int row = b + 256*rsel;          // block owns rows {b, b+256}
  const bool v = row < NN;
  float* scratch = (float*)(smem + PK_L);
  char* pb8 = (char*)smem + PERSIST_OFF;
  float* pSh = (float*)pb8;
  float* pSa = pSh + 256;
  float* pSg = pSa + 256;
  float* pDx = pSg + 256;
  int*   pCnt = (int*)(pDx + 8);
  uint4* sEr = (uint4*)(pb8 + 3120);

  // stage packed weights -> LDS via direct global->LDS DMA
  for (int idx = tid; idx < PK_L/4; idx += 1024)
    __builtin_amdgcn_global_load_lds(
        (const __attribute__((address_space(1))) unsigned*)(pkl + idx*4),
        (__attribute__((address_space(3))) unsigned*)(smem + idx*4),
        16, 0, 0);
  // load own-row h/A, zero agg/dx
  if (tid < 256) {
    int rr = b + 256*(tid >> 7);
    if (rr < NN) {
      pSh[tid] = h[rr*128 + (tid & 127)];
      pSa[tid] = A[rr*128 + (tid & 127)];
    }
    pSg[tid] = 0.f;
  } else if (tid < 264) pDx[tid - 256] = 0.f;
  // build radius graph for own rows (internal syncthreads drain the DMA)
  scan_rows2(row, rsel, t512, v, x_src, sEr, pCnt);
  __syncthreads();
  edge_phase(hbf_in, smem, scratch, pSa, pSg, pDx, pCnt, sEr,
             eb2l, cb1l, cw2l, b < 128);
  __syncthreads();
  if (v && t512 < 3) {
    float xn = x_src[row*3 + t512] + pDx[rsel*4 + t512];
    x_dst[row*3 + t512] = meanp ? (xn - meanp[t512]) : xn;
  }
  if (do_node)
    node_phase4(nW1l, nb1l, nW2l, nb2l, eW1n, eb1n, hbf_out, h, A,
                pSh, pSa, pSg, scratch, rsel, q4, o, row, v);
}

extern "C" void kernel_launch(void* const* d_in, const int* in_sizes, int n_in,
                              void* d_out, int out_size, void* d_ws, size_t ws_size,
                              hipStream_t stream){
  const float* z      = (const float*)d_in[0];
  const float* anchor = (const float*)d_in[1];
  const float* projW  = (const float*)d_in[2];
  const float* projb  = (const float*)d_in[3];
  const float* eW1    = (const float*)d_in[4];
  const float* eb1    = (const float*)d_in[5];
  const float* eW2    = (const float*)d_in[6];
  const float* eb2    = (const float*)d_in[7];
  const float* nW1    = (const float*)d_in[8];
  const float* nb1    = (const float*)d_in[9];
  const float* nW2    = (const float*)d_in[10];
  const float* nb2    = (const float*)d_in[11];
  const float* cW1    = (const float*)d_in[12];
  const float* cb1    = (const float*)d_in[13];
  const float* cW2    = (const float*)d_in[14];
  float* out = (float*)d_out;

  char* w = (char*)d_ws;
  float* xA  = (float*)(w + O_XA);
  float* xB  = (float*)(w + O_XB);
  float* h   = (float*)(w + O_H);
  float* A   = (float*)(w + O_A);
  unsigned short* hbf0 = (unsigned short*)(w + O_HBF0);
  unsigned short* hbf1 = (unsigned short*)(w + O_HBF1);
  float* meanw = (float*)(w + O_MEAN);
  unsigned* pk = (unsigned*)(w + O_PK);

  hipFuncSetAttribute((const void*)k_layer, hipFuncAttributeMaxDynamicSharedMemorySize, K_SMEM);

  k_init<<<256, 512, 0, stream>>>(eW1, eW2, cW1, pk, anchor, z, projW, projb,
                                  eb1, h, hbf0, A, meanw);
  // layer 0: anchor -> xB; reads hbf0, node -> hbf1, A(l1)
  k_layer<<<256, 1024, K_SMEM, stream>>>(pk, anchor, xB, hbf0, hbf1, h, A,
      eb2, cb1, cW2,
      nW1, nb1, nW2, nb2, eW1 + 272*128, eb1 + 128,
      (const float*)nullptr, 1);
  // layer 1: xB -> xA; reads hbf1, node -> hbf0, A(l2)
  k_layer<<<256, 1024, K_SMEM, stream>>>(pk + PK_L, xB, xA, hbf1, hbf0, h, A,
      eb2 + 128, cb1 + 128, cW2 + 128,
      nW1 + 256*128, nb1 + 128, nW2 + 128*128, nb2 + 128,
      eW1 + 2*272*128, eb1 + 256,
      (const float*)nullptr, 1);
  // layer 2: xA -> out (centered); reads hbf0 (layer-1 node output); no node
  k_layer<<<256, 1024, K_SMEM, stream>>>(pk + 2*PK_L, xA, out, hbf0, hbf1, h, A,
      eb2 + 256, cb1 + 256, cW2 + 256,
      nW1, nb1, nW2, nb2, eW1, eb1,
      meanw, 0);
}

// Round 12
// 172.223 us; speedup vs baseline: 1.7071x; 1.2200x over previous
//
#include <hip/hip_runtime.h>
#include <hip/hip_bf16.h>

// Problem constants
#define NN 384
#define CUTOFF2 144.0f
#define GAMMA 1.7777778f   // (16/12)^2

// packed B-frag layout per layer (u32 units): [W1b 8192 | We 2048 | W2 8192 | C1 8192]
#define PK_L 26624
#define PK_WE 8192
#define PK_W2 10240
#define PK_C1 18432

#define STG_F32 1152                       // 32 rows x 36 f32 per-wave stage
#define SCRATCH_B (8*STG_F32*4)            // 36864 B
#define PERSIST_OFF (PK_L*4 + SCRATCH_B)   // 143360 B
// persist: pSh 1024 | pSa 1024 | pSg 1024 | pDx 32 | pCnt 8 | pad | sErec 12288 @3120
#define K_SMEM (PERSIST_OFF + 15408)       // 158768 B <= 160 KiB -> 1 block/CU

// ws byte offsets
#define O_H    9216        // 384*128 f32
#define O_A    205824      // 384*128 f32
#define O_XA   0
#define O_XB   4608
#define O_HBF0 599040      // 384*128 bf16
#define O_HBF1 697344      // 384*128 bf16 (double buffer)
#define O_MEAN 3076112
#define O_PK   3076160

typedef __bf16 bf16x8 __attribute__((ext_vector_type(8)));
typedef float f32x4 __attribute__((ext_vector_type(4)));

union ER { struct { float dx, dy, dz; unsigned j; } e; uint4 u4; };

__device__ __forceinline__ unsigned short f2bf(float f){
  unsigned u = __float_as_uint(f);
  return (unsigned short)((u + 0x7fffu + ((u >> 16) & 1u)) >> 16);  // RNE
}
__device__ __forceinline__ unsigned pk2(float a, float b){
  return ((unsigned)f2bf(b) << 16) | f2bf(a);
}
__device__ __forceinline__ float silu(float x){ return x / (1.0f + __expf(-x)); }

// ---- scan own rows -> LDS edge records {diff,j}; count in pCnt[rowsel]
__device__ __forceinline__ void scan_rows(
    int row, int rowsel, int t256, bool v, const float* __restrict__ x,
    uint4* sEr, int* pCnt){
  int* scnt = &pCnt[rowsel];
  if (t256 == 0) *scnt = 0;
  __syncthreads();
  if (v) {
    float xi0 = x[row*3], xi1 = x[row*3+1], xi2 = x[row*3+2];
    for (int j = t256; j < 384; j += 256) {
      float d0 = xi0-x[j*3], d1 = xi1-x[j*3+1], d2 = xi2-x[j*3+2];
      float dd = d0*d0 + d1*d1 + d2*d2;
      bool msk = ((dd < CUTOFF2) && (j != row)) || (j == row-1) || (j == row+1);
      if (msk) {
        int ss = atomicAdd(scnt, 1);
        ER er; er.e.dx = d0; er.e.dy = d1; er.e.dz = d2; er.e.j = (unsigned)j;
        sEr[rowsel*384 + ss] = er.u4;
      }
    }
  }
  __syncthreads();
  if (v) {
    int cnt = *scnt;
    int p = (32 - (cnt & 31)) & 31;
    if (t256 < p) {
      ER er; er.e.dx = 0.f; er.e.dy = 0.f; er.e.dz = 0.f; er.e.j = (unsigned)row;
      sEr[rowsel*384 + cnt + t256] = er.u4;
    }
  }
  // caller's __syncthreads (pre-edge) makes pads visible
}

// ---- C-layout -> A-frag transpose via per-wave f32 LDS pad (wave-private, no fences)
#define TRANSFORM(VA, VB, FA, FB)                                              \
  _Pragma("unroll")                                                            \
  for (int c = 0; c < 4; ++c) {                                                \
    _Pragma("unroll")                                                          \
    for (int tl = 0; tl < 2; ++tl) {                                           \
      int t = 2*c + tl;                                                        \
      _Pragma("unroll")                                                        \
      for (int r = 0; r < 4; ++r) {                                            \
        stg[(quad*4 + r)*36 + tl*16 + col0] = VA[t][r];                        \
        stg[(16 + quad*4 + r)*36 + tl*16 + col0] = VB[t][r];                   \
      }                                                                        \
    }                                                                          \
    float4 lo = *(const float4*)(stg + col0*36 + quad*8);                      \
    float4 hi = *(const float4*)(stg + col0*36 + quad*8 + 4);                  \
    FA[c].u = make_uint4(pk2(lo.x,lo.y), pk2(lo.z,lo.w),                       \
                         pk2(hi.x,hi.y), pk2(hi.z,hi.w));                      \
    float4 lo2 = *(const float4*)(stg + (16 + col0)*36 + quad*8);              \
    float4 hi2 = *(const float4*)(stg + (16 + col0)*36 + quad*8 + 4);          \
    FB[c].u = make_uint4(pk2(lo2.x,lo2.y), pk2(lo2.z,lo2.w),                   \
                         pk2(hi2.x,hi2.y), pk2(hi2.z,hi2.w));                  \
  }

// ---- MFMA edge phase: block-local 32-edge units, LDS agg/dx (verified R4 body)
__device__ __forceinline__ void edge_phase(
    const unsigned short* __restrict__ hbf,
    const unsigned* smem, float* scratch,
    const float* pSa, float* pSg, float* pDx, const int* pCnt, const uint4* sEr,
    const float* __restrict__ eb2g, const float* __restrict__ cb1g,
    const float* __restrict__ cw2g, int valid1){
  const int tid = threadIdx.x, q = tid & 63, s = tid >> 6;
  const int col0 = q & 15, quad = q >> 4;
  float eb2v[8], cb1v[8], cw2v[8];
  #pragma unroll
  for (int t = 0; t < 8; ++t) {
    int c = t*16 + col0;
    eb2v[t] = eb2g[c]; cb1v[t] = cb1g[c]; cw2v[t] = cw2g[c];
  }
  float* stg = scratch + s*STG_F32;
  const f32x4 z4 = {0.f, 0.f, 0.f, 0.f};
  union U8 { uint4 u; bf16x8 v; };

  const int nu0 = (pCnt[0] + 31) >> 5;
  const int nu1 = valid1 ? ((pCnt[1] + 31) >> 5) : 0;
  const int nu = nu0 + nu1;

  for (int k = s; k < nu; k += 8) {
    const int rs = (k < nu0) ? 0 : 1;
    const int ub = (k < nu0) ? k : k - nu0;
    int nvalid = pCnt[rs] - ub*32; if (nvalid > 32) nvalid = 32;
    float Aval[8];
    #pragma unroll
    for (int t = 0; t < 8; ++t) Aval[t] = pSa[rs*128 + t*16 + col0];
    ER e0, e1;
    e0.u4 = sEr[rs*384 + ub*32 + col0];
    e1.u4 = sEr[rs*384 + ub*32 + 16 + col0];
    const int j0 = (int)e0.e.j, j1 = (int)e1.e.j;
    const float d0x = e0.e.dx, d0y = e0.e.dy, d0z = e0.e.dz;
    const float d1x = e1.e.dx, d1y = e1.e.dy, d1z = e1.e.dz;
    const float dd0 = sqrtf(d0x*d0x + d0y*d0y + d0z*d0z);
    const float dd1 = sqrtf(d1x*d1x + d1y*d1y + d1z*d1z);

    U8 ha0[4], ha1[4];
    #pragma unroll
    for (int c = 0; c < 4; ++c) {
      ha0[c].u = *(const uint4*)(hbf + j0*128 + c*32 + quad*8);
      ha1[c].u = *(const uint4*)(hbf + j1*128 + c*32 + quad*8);
    }

    U8 cve0, cve1;
    if (q < 32) {
      #pragma unroll
      for (int tp = 0; tp < 4; ++tp) {
        float k0 = (float)(quad*8 + 2*tp);
        float t00 = dd0 - 0.8f*k0, t01 = dd0 - 0.8f*(k0+1.f);
        float t10 = dd1 - 0.8f*k0, t11 = dd1 - 0.8f*(k0+1.f);
        (&cve0.u.x)[tp] = pk2(__expf(-GAMMA*t00*t00), __expf(-GAMMA*t01*t01));
        (&cve1.u.x)[tp] = pk2(__expf(-GAMMA*t10*t10), __expf(-GAMMA*t11*t11));
      }
    } else { cve0.u = make_uint4(0,0,0,0); cve1.u = make_uint4(0,0,0,0); }

    // GEMM1: m1 = silu(h_j@W1b + e@We + A_i), 32 rows
    f32x4 acc0[8], acc1[8];
    #pragma unroll
    for (int t = 0; t < 8; ++t) { acc0[t] = z4; acc1[t] = z4; }
    #pragma unroll
    for (int t = 0; t < 8; ++t) {
      #pragma unroll
      for (int c = 0; c < 4; ++c) {
        bf16x8 w = *(const bf16x8*)(smem + ((t*4 + c)*64 + q)*4);
        acc0[t] = __builtin_amdgcn_mfma_f32_16x16x32_bf16(ha0[c].v, w, acc0[t], 0, 0, 0);
        acc1[t] = __builtin_amdgcn_mfma_f32_16x16x32_bf16(ha1[c].v, w, acc1[t], 0, 0, 0);
      }
      bf16x8 we = *(const bf16x8*)(smem + PK_WE + (t*64 + q)*4);
      acc0[t] = __builtin_amdgcn_mfma_f32_16x16x32_bf16(cve0.v, we, acc0[t], 0, 0, 0);
      acc1[t] = __builtin_amdgcn_mfma_f32_16x16x32_bf16(cve1.v, we, acc1[t], 0, 0, 0);
    }
    #pragma unroll
    for (int t = 0; t < 8; ++t)
      #pragma unroll
      for (int r = 0; r < 4; ++r) {
        acc0[t][r] = silu(acc0[t][r] + Aval[t]);
        acc1[t][r] = silu(acc1[t][r] + Aval[t]);
      }

    U8 a20[4], a21[4];
    TRANSFORM(acc0, acc1, a20, a21);

    // GEMM2: m = silu(m1@eW2 + eb2)
    f32x4 m0[8], m1v[8];
    #pragma unroll
    for (int t = 0; t < 8; ++t) { m0[t] = z4; m1v[t] = z4; }
    #pragma unroll
    for (int t = 0; t < 8; ++t)
      #pragma unroll
      for (int c = 0; c < 4; ++c) {
        bf16x8 w = *(const bf16x8*)(smem + PK_W2 + ((t*4 + c)*64 + q)*4);
        m0[t] = __builtin_amdgcn_mfma_f32_16x16x32_bf16(a20[c].v, w, m0[t], 0, 0, 0);
        m1v[t] = __builtin_amdgcn_mfma_f32_16x16x32_bf16(a21[c].v, w, m1v[t], 0, 0, 0);
      }
    #pragma unroll
    for (int t = 0; t < 8; ++t) {
      float cs = 0.f;
      #pragma unroll
      for (int r = 0; r < 4; ++r) {
        m0[t][r] = silu(m0[t][r] + eb2v[t]);
        m1v[t][r] = silu(m1v[t][r] + eb2v[t]);
        if (quad*4 + r < nvalid) cs += m0[t][r];
        if (16 + quad*4 + r < nvalid) cs += m1v[t][r];
      }
      cs += __shfl_xor(cs, 16); cs += __shfl_xor(cs, 32);
      if (q < 16) atomicAdd(&pSg[rs*128 + t*16 + q], cs);   // LDS atomic
    }

    U8 a30[4], a31[4];
    TRANSFORM(m0, m1v, a30, a31);

    // GEMM3: c1 = silu(m@cW1 + cb1); w_row = c1 . cW2
    f32x4 c30[8], c31[8];
    #pragma unroll
    for (int t = 0; t < 8; ++t) { c30[t] = z4; c31[t] = z4; }
    #pragma unroll
    for (int t = 0; t < 8; ++t)
      #pragma unroll
      for (int c = 0; c < 4; ++c) {
        bf16x8 w = *(const bf16x8*)(smem + PK_C1 + ((t*4 + c)*64 + q)*4);
        c30[t] = __builtin_amdgcn_mfma_f32_16x16x32_bf16(a30[c].v, w, c30[t], 0, 0, 0);
        c31[t] = __builtin_amdgcn_mfma_f32_16x16x32_bf16(a31[c].v, w, c31[t], 0, 0, 0);
      }
    float p0[4], p1[4];
    #pragma unroll
    for (int r = 0; r < 4; ++r) {
      float pa = 0.f, pb = 0.f;
      #pragma unroll
      for (int t = 0; t < 8; ++t) {
        pa += silu(c30[t][r] + cb1v[t]) * cw2v[t];
        pb += silu(c31[t][r] + cb1v[t]) * cw2v[t];
      }
      if (quad*4 + r >= nvalid) pa = 0.f;
      if (16 + quad*4 + r >= nvalid) pb = 0.f;
      p0[r] = pa; p1[r] = pb;
    }
    #pragma unroll
    for (int r = 0; r < 4; ++r)
      #pragma unroll
      for (int off = 1; off < 16; off <<= 1) {
        p0[r] += __shfl_xor(p0[r], off);
        p1[r] += __shfl_xor(p1[r], off);
      }
    float dx0 = 0.f, dx1 = 0.f, dx2 = 0.f;
    #pragma unroll
    for (int r = 0; r < 4; ++r) {
      int el = quad*4 + r;
      float s0 = __shfl(d0x, el), s1 = __shfl(d0y, el), s2 = __shfl(d0z, el);
      if (col0 == 0) { dx0 += p0[r]*s0; dx1 += p0[r]*s1; dx2 += p0[r]*s2; }
      float u0 = __shfl(d1x, el), u1 = __shfl(d1y, el), u2 = __shfl(d1z, el);
      if (col0 == 0) { dx0 += p1[r]*u0; dx1 += p1[r]*u1; dx2 += p1[r]*u2; }
    }
    dx0 += __shfl_xor(dx0, 16); dx0 += __shfl_xor(dx0, 32);
    dx1 += __shfl_xor(dx1, 16); dx1 += __shfl_xor(dx1, 32);
    dx2 += __shfl_xor(dx2, 16); dx2 += __shfl_xor(dx2, 32);
    if (q == 0) {
      atomicAdd(&pDx[rs*4 + 0], dx0);   // LDS atomic
      atomicAdd(&pDx[rs*4 + 1], dx1);
      atomicAdd(&pDx[rs*4 + 2], dx2);
    }
  }
}

// ---- node phase (verified R4 body: h/agg/A LDS-resident, writes h/A/hbf_out global)
__device__ __forceinline__ void node_phase(
    const float* __restrict__ nW1l, const float* __restrict__ nb1l,
    const float* __restrict__ nW2l, const float* __restrict__ nb2l,
    const float* __restrict__ eW1n, const float* __restrict__ eb1n,
    unsigned short* __restrict__ hbf_out,
    float* __restrict__ hg, float* __restrict__ Ag,
    float* pSh, float* pSa, const float* pSg,
    float* scratch, int rowsel, int half, int o, int row, bool v){
  float* sb = scratch + rowsel*768;
  float* st = sb; float* part = sb + 128;

  float aa = 0.f;
  if (v) {
    const float* src = half ? (pSg + rowsel*128) : (pSh + rowsel*128);
    const float* wb  = nW1l + half*128*128;
    float a0=0,a1=0,a2=0,a3=0;
    #pragma unroll 16
    for (int k = 0; k < 128; k += 4) {
      a0 += src[k]   * wb[k*128 + o];
      a1 += src[k+1] * wb[(k+1)*128 + o];
      a2 += src[k+2] * wb[(k+2)*128 + o];
      a3 += src[k+3] * wb[(k+3)*128 + o];
    }
    aa = (a0+a1)+(a2+a3);
    if (half) part[o] = aa;
  }
  __syncthreads();
  if (v && !half) st[o] = silu(nb1l[o] + aa + part[o]);
  __syncthreads();
  float bb = 0.f;
  if (v) {
    int k0 = half*64;
    float b0=0,b1=0,b2=0,b3=0;
    #pragma unroll 16
    for (int k = k0; k < k0+64; k += 4) {
      b0 += st[k]   * nW2l[k*128 + o];
      b1 += st[k+1] * nW2l[(k+1)*128 + o];
      b2 += st[k+2] * nW2l[(k+2)*128 + o];
      b3 += st[k+3] * nW2l[(k+3)*128 + o];
    }
    bb = (b0+b1)+(b2+b3);
    if (half) part[o] = bb;
  }
  __syncthreads();
  if (v && !half) {
    float hn = pSh[rowsel*128 + o] + nb2l[o] + bb + part[o];
    pSh[rowsel*128 + o] = hn;
    hg[row*128 + o] = hn;
    hbf_out[row*128 + o] = f2bf(hn);
  }
  __syncthreads();
  float cc = 0.f;
  if (v) {
    const float* shn = pSh + rowsel*128;
    int k0 = half*64;
    float c0=0,c1=0,c2=0,c3=0;
    #pragma unroll 16
    for (int k = k0; k < k0+64; k += 4) {
      c0 += shn[k]   * eW1n[k*128 + o];
      c1 += shn[k+1] * eW1n[(k+1)*128 + o];
      c2 += shn[k+2] * eW1n[(k+2)*128 + o];
      c3 += shn[k+3] * eW1n[(k+3)*128 + o];
    }
    cc = (c0+c1)+(c2+c3);
    if (half) part[o] = cc;
  }
  __syncthreads();
  if (v && !half) Ag[row*128 + o] = eb1n[o] + cc + part[o];
}

// ---- K1: pack + mean + proj + A0 (row-owner: block b owns rows {b, b+256})
__global__ __launch_bounds__(512) void k_init(
    const float* __restrict__ eW1, const float* __restrict__ eW2,
    const float* __restrict__ cW1, unsigned* __restrict__ pk,
    const float* __restrict__ anchor, const float* __restrict__ z,
    const float* __restrict__ pW, const float* __restrict__ pbias,
    const float* __restrict__ eb1, float* __restrict__ h,
    unsigned short* __restrict__ hbf, float* __restrict__ A,
    float* __restrict__ meanw){
  __shared__ float sb2[2*768];
  __shared__ float ssum[3];
  const int b = blockIdx.x, tid = threadIdx.x;
  const int rowsel = tid >> 8, half = (tid >> 7) & 1, o = tid & 127;
  // weight pack (256*512 = 131072 slots cover 3*PK_L = 79872)
  {
    int t = b*512 + tid;
    if (t < 3*PK_L) {
      int layer = t / PK_L, r = t % PK_L;
      const float* src; int fr; int isWe = 0;
      if (r < PK_WE)        { fr = r;          src = eW1 + (layer*272 + 128)*128; }
      else if (r < PK_W2)   { fr = r - PK_WE;  src = eW1 + (layer*272 + 256)*128; isWe = 1; }
      else if (r < PK_C1)   { fr = r - PK_W2;  src = eW2 + layer*128*128; }
      else                  { fr = r - PK_C1;  src = cW1 + layer*128*128; }
      int tp = fr & 3, ll = (fr >> 2) & 63, nc = fr >> 8;
      int n, k;
      if (!isWe) { n = nc >> 2; int c = nc & 3; k = c*32 + ((ll>>4)<<3) + 2*tp; }
      else       { n = nc;                      k = ((ll>>4)<<3) + 2*tp; }
      int nn2 = n*16 + (ll & 15);
      float w0, w1;
      if (isWe) { w0 = (k < 16)   ? src[k*128+nn2]     : 0.f;
                  w1 = (k+1 < 16) ? src[(k+1)*128+nn2] : 0.f; }
      else      { w0 = src[k*128+nn2]; w1 = src[(k+1)*128+nn2]; }
      pk[t] = ((unsigned)f2bf(w1) << 16) | f2bf(w0);
    }
  }
  if (b == 0) {                          // anchor mean
    if (tid < 3) ssum[tid] = 0.f;
    __syncthreads();
    if (tid < 384) {
      atomicAdd(&ssum[0], anchor[tid*3]);
      atomicAdd(&ssum[1], anchor[tid*3+1]);
      atomicAdd(&ssum[2], anchor[tid*3+2]);
    }
    __syncthreads();
    if (tid < 3) meanw[tid] = ssum[tid]*(1.f/384.f);
  }
  // proj + A-precompute for own rows
  const int row = b + 256*rowsel;
  const bool v = row < NN;
  float* sb = sb2 + rowsel*768;
  float* sh = sb; float* part = sb + 512; float* sz = sb + 640;
  if (v && half == 0 && o < 64) sz[o] = z[row*64 + o];
  __syncthreads();
  float pp = 0.f;
  if (v) {
    int k0 = half*32;
    float p0=0,p1=0,p2=0,p3=0;
    #pragma unroll 8
    for (int k = k0; k < k0+32; k += 4) {
      p0 += sz[k]   * pW[k*128 + o];
      p1 += sz[k+1] * pW[(k+1)*128 + o];
      p2 += sz[k+2] * pW[(k+2)*128 + o];
      p3 += sz[k+3] * pW[(k+3)*128 + o];
    }
    pp = (p0+p1)+(p2+p3);
    if (half) part[o] = pp;
  }
  __syncthreads();
  if (v && !half) {
    float hh = pbias[o] + pp + part[o];
    h[row*128 + o] = hh; sh[o] = hh;
    hbf[row*128 + o] = f2bf(hh);
  }
  __syncthreads();
  float cc = 0.f;
  if (v) {
    int k0 = half*64;
    float c0=0,c1=0,c2=0,c3=0;
    #pragma unroll 16
    for (int k = k0; k < k0+64; k += 4) {
      c0 += sh[k]   * eW1[k*128 + o];
      c1 += sh[k+1] * eW1[(k+1)*128 + o];
      c2 += sh[k+2] * eW1[(k+2)*128 + o];
      c3 += sh[k+3] * eW1[(k+3)*128 + o];
    }
    cc = (c0+c1)+(c2+c3);
    if (half) part[o] = cc;
  }
  __syncthreads();
  if (v && !half) A[row*128 + o] = eb1[o] + cc + part[o];
}

// ---- K2: one layer = scan + edge + xup (+ node). Regular launch, no fences.
__global__ __launch_bounds__(512, 1) void k_layer(
    const unsigned* __restrict__ pkl,
    const float* __restrict__ x_src, float* __restrict__ x_dst,
    const unsigned short* __restrict__ hbf_in, unsigned short* __restrict__ hbf_out,
    float* __restrict__ h, float* __restrict__ A,
    const float* __restrict__ eb2l, const float* __restrict__ cb1l,
    const float* __restrict__ cw2l,
    const float* __restrict__ nW1l, const float* __restrict__ nb1l,
    const float* __restrict__ nW2l, const float* __restrict__ nb2l,
    const float* __restrict__ eW1n, const float* __restrict__ eb1n,
    const float* __restrict__ meanp, int do_node){
  extern __shared__ unsigned smem[];
  const int b = blockIdx.x, tid = threadIdx.x;
  const int rowsel = tid >> 8, half = (tid >> 7) & 1, o = tid & 127, t256 = tid & 255;
  const int row = b + 256*rowsel;        // block owns rows {b, b+256}
  const bool v = row < NN;
  float* scratch = (float*)(smem + PK_L);
  char* pb8 = (char*)smem + PERSIST_OFF;
  float* pSh = (float*)pb8;
  float* pSa = pSh + 256;
  float* pSg = pSa + 256;
  float* pDx = pSg + 256;
  int*   pCnt = (int*)(pDx + 8);
  uint4* sEr = (uint4*)(pb8 + 3120);

  // stage packed weights -> LDS via direct global->LDS DMA (no VGPR round-trip).
  // idx = tid + k*512: wave-uniform LDS base + lane*16 — the required layout.
  #pragma unroll
  for (int idx = tid; idx < PK_L/4; idx += 512)
    __builtin_amdgcn_global_load_lds(
        (const __attribute__((address_space(1))) unsigned*)(pkl + idx*4),
        (__attribute__((address_space(3))) unsigned*)(smem + idx*4),
        16, 0, 0);
  // load own-row h/A, zero agg/dx
  if (tid < 256) {
    int rr = b + 256*(tid >> 7);
    if (rr < NN) {
      pSh[tid] = h[rr*128 + (tid & 127)];
      pSa[tid] = A[rr*128 + (tid & 127)];
    }
    pSg[tid] = 0.f;
  } else if (tid < 264) pDx[tid - 256] = 0.f;
  // build radius graph for own rows into LDS (internal syncthreads drain the DMA)
  scan_rows(row, rowsel, t256, v, x_src, sEr, pCnt);
  __syncthreads();
  edge_phase(hbf_in, smem, scratch, pSa, pSg, pDx, pCnt, sEr,
             eb2l, cb1l, cw2l, b < 128);
  __syncthreads();
  if (v && half == 0 && o < 3) {
    float xn = x_src[row*3 + o] + pDx[rowsel*4 + o];
    x_dst[row*3 + o] = meanp ? (xn - meanp[o]) : xn;
  }
  if (do_node)
    node_phase(nW1l, nb1l, nW2l, nb2l, eW1n, eb1n, hbf_out, h, A,
               pSh, pSa, pSg, scratch, rowsel, half, o, row, v);
}

extern "C" void kernel_launch(void* const* d_in, const int* in_sizes, int n_in,
                              void* d_out, int out_size, void* d_ws, size_t ws_size,
                              hipStream_t stream){
  const float* z      = (const float*)d_in[0];
  const float* anchor = (const float*)d_in[1];
  const float* projW  = (const float*)d_in[2];
  const float* projb  = (const float*)d_in[3];
  const float* eW1    = (const float*)d_in[4];
  const float* eb1    = (const float*)d_in[5];
  const float* eW2    = (const float*)d_in[6];
  const float* eb2    = (const float*)d_in[7];
  const float* nW1    = (const float*)d_in[8];
  const float* nb1    = (const float*)d_in[9];
  const float* nW2    = (const float*)d_in[10];
  const float* nb2    = (const float*)d_in[11];
  const float* cW1    = (const float*)d_in[12];
  const float* cb1    = (const float*)d_in[13];
  const float* cW2    = (const float*)d_in[14];
  float* out = (float*)d_out;

  char* w = (char*)d_ws;
  float* xA  = (float*)(w + O_XA);
  float* xB  = (float*)(w + O_XB);
  float* h   = (float*)(w + O_H);
  float* A   = (float*)(w + O_A);
  unsigned short* hbf0 = (unsigned short*)(w + O_HBF0);
  unsigned short* hbf1 = (unsigned short*)(w + O_HBF1);
  float* meanw = (float*)(w + O_MEAN);
  unsigned* pk = (unsigned*)(w + O_PK);

  hipFuncSetAttribute((const void*)k_layer, hipFuncAttributeMaxDynamicSharedMemorySize, K_SMEM);

  k_init<<<256, 512, 0, stream>>>(eW1, eW2, cW1, pk, anchor, z, projW, projb,
                                  eb1, h, hbf0, A, meanw);
  // layer 0: anchor -> xB; reads hbf0, node -> hbf1, A(l1)
  k_layer<<<256, 512, K_SMEM, stream>>>(pk, anchor, xB, hbf0, hbf1, h, A,
      eb2, cb1, cW2,
      nW1, nb1, nW2, nb2, eW1 + 272*128, eb1 + 128,
      (const float*)nullptr, 1);
  // layer 1: xB -> xA; reads hbf1, node -> hbf0, A(l2)
  k_layer<<<256, 512, K_SMEM, stream>>>(pk + PK_L, xB, xA, hbf1, hbf0, h, A,
      eb2 + 128, cb1 + 128, cW2 + 128,
      nW1 + 256*128, nb1 + 128, nW2 + 128*128, nb2 + 128,
      eW1 + 2*272*128, eb1 + 256,
      (const float*)nullptr, 1);
  // layer 2: xA -> out (centered); reads hbf0 (layer-1 node output); no node
  k_layer<<<256, 512, K_SMEM, stream>>>(pk + 2*PK_L, xA, out, hbf0, hbf1, h, A,
      eb2 + 256, cb1 + 256, cW2 + 256,
      nW1, nb1, nW2, nb2, eW1, eb1,
      meanw, 0);
}